// Round 3
// baseline (3684.870 us; speedup 1.0000x reference)
//
#include <hip/hip_runtime.h>
#include <hip/hip_bf16.h>

#define BATCH 128
#define SEQ   256
#define EMB   256
#define HID   512
#define NCLS  50257

typedef unsigned short u16;
typedef __attribute__((ext_vector_type(8))) short short8;
typedef __attribute__((ext_vector_type(4))) short s16x4;
typedef __attribute__((ext_vector_type(4))) float f32x4;

__device__ __forceinline__ u16 f2bf(float f) {
    unsigned x = __builtin_bit_cast(unsigned, f);
    x += 0x7FFFu + ((x >> 16) & 1u);
    return (u16)(x >> 16);
}
__device__ __forceinline__ float sigm(float x) { return 1.f / (1.f + __expf(-x)); }
__device__ __forceinline__ float tanh_(float x) {
    x = fminf(15.f, fmaxf(-15.f, x));
    float e = __expf(2.f * x);
    return (e - 1.f) / (e + 1.f);
}
__device__ __forceinline__ f32x4 zero4() { f32x4 v; v[0]=0.f; v[1]=0.f; v[2]=0.f; v[3]=0.f; return v; }

// ---------------------------------------------------------------------------
// Fused LSTM recurrence (embed -> 4-gate pre-activation -> gate math), 256
// steps. Cooperative, 128 wgs: wg=(bc 0..3)x(cc 0..31) owns batch rows
// [32*bc,+32) and H-cols [16*cc,+16). One gate per wave; W_x and W_h slices
// converted f32->bf16 once and held in VGPRs. E-tile double-buffered in LDS
// (prefetch t+1 overlaps the cross-wg sync). Sync per batch-group: release
// atomic add / acquire spin on an L2 counter, fan-in 32.
// LDS map (bytes): [0,32768) HA = H tile [32][1024B] swz (also 1-time weight
// staging); [32768,65536) E0/E1 [32][512B] swz; [65536,73984) pre[64][33]f32;
// [73984,76032) Cst[32][16]f32.
// ---------------------------------------------------------------------------
__global__ __launch_bounds__(256, 1) void rnn_kernel(
    const int* __restrict__ X, const float* __restrict__ Cemb,
    const float* __restrict__ Wxi, const float* __restrict__ Wxf,
    const float* __restrict__ Wxo, const float* __restrict__ Wxc,
    const float* __restrict__ Whi, const float* __restrict__ Whf,
    const float* __restrict__ Who, const float* __restrict__ Whc,
    const float* __restrict__ bi, const float* __restrict__ bfv,
    const float* __restrict__ bo, const float* __restrict__ bcv,
    u16* __restrict__ Hbuf, unsigned* __restrict__ cnt)
{
    __shared__ __align__(16) char smem[76032];
    u16*   HA  = (u16*)smem;
    float* pre = (float*)(smem + 65536);
    float* Cst = (float*)(smem + 73984);

    const int wg = blockIdx.x;
    const int bc = wg >> 5, cc = wg & 31, b0 = bc * 32;
    const int tid = threadIdx.x, lane = tid & 63, wave = tid >> 6;
    const int ec = tid & 15, ebl = tid >> 4;

    const float* WxA[4] = {Wxi, Wxf, Wxo, Wxc};
    const float* WhA[4] = {Whi, Whf, Who, Whc};

    const float bias_i = bi [cc * 16 + ec];
    const float bias_f = bfv[cc * 16 + ec];
    const float bias_o = bo [cc * 16 + ec];
    const float bias_c = bcv[cc * 16 + ec];

    // ---- one-time: W_x slice [256 k][16 n] (f32 -> bf16) -> bregX ----
    short8 bregX[8];
    {
        const float* Wx = WxA[wave];
        u16* dst = HA + wave * 4096;
#pragma unroll
        for (int it = 0; it < 16; ++it) {
            int e = it * 256 + lane * 4;          // 0..4095
            int k = e >> 4, c4 = (e & 15) >> 2;
            f32x4 v = *(const f32x4*)(Wx + (size_t)k * HID + cc * 16 + c4 * 4);
            s16x4 s;
#pragma unroll
            for (int j = 0; j < 4; ++j) s[j] = (short)f2bf(v[j]);
            *(s16x4*)(dst + k * 16 + c4 * 4) = s;
        }
    }
    __syncthreads();
    {
        const u16* tile = HA + wave * 4096;
#pragma unroll
        for (int ks = 0; ks < 8; ++ks) {
            short8 v;
#pragma unroll
            for (int i = 0; i < 8; ++i)
                v[i] = (short)tile[(ks * 32 + (lane >> 4) * 8 + i) * 16 + (lane & 15)];
            bregX[ks] = v;
        }
    }
    __syncthreads();

    // ---- one-time: W_h slice [512 k][16 n] per gate -> bregH (2 passes) ----
    short8 bregH[16];
    for (int pass = 0; pass < 2; ++pass) {
        for (int gi = 0; gi < 2; ++gi) {
            const float* W = WhA[2 * pass + gi];
#pragma unroll
            for (int it = 0; it < 8; ++it) {
                int e = it * 1024 + tid * 4;      // 0..8191
                int k = e >> 4, c4 = (e & 15) >> 2;
                f32x4 v = *(const f32x4*)(W + (size_t)k * HID + cc * 16 + c4 * 4);
                s16x4 s;
#pragma unroll
                for (int j = 0; j < 4; ++j) s[j] = (short)f2bf(v[j]);
                *(s16x4*)(HA + gi * 8192 + k * 16 + c4 * 4) = s;
            }
        }
        __syncthreads();
        if ((wave >> 1) == pass) {
            const u16* tile = HA + (wave & 1) * 8192;
#pragma unroll
            for (int ks = 0; ks < 16; ++ks) {
                short8 v;
#pragma unroll
                for (int i = 0; i < 8; ++i)
                    v[i] = (short)tile[(ks * 32 + (lane >> 4) * 8 + i) * 16 + (lane & 15)];
                bregH[ks] = v;
            }
        }
        __syncthreads();
    }

    // ---- Cst = 0, stage E_0 into buf 0 ----
    for (int i = tid; i < 512; i += 256) Cst[i] = 0.f;
    {
        int row = tid >> 3, seg = tid & 7;
        int tok = X[(b0 + row) * SEQ + 0];
        const float* src = Cemb + (size_t)tok * EMB + seg * 32;
        char* eb = smem + 32768;
#pragma unroll
        for (int i = 0; i < 4; ++i) {
            f32x4 a = *(const f32x4*)(src + i * 8);
            f32x4 b = *(const f32x4*)(src + i * 8 + 4);
            short8 v;
#pragma unroll
            for (int j = 0; j < 4; ++j) { v[j] = (short)f2bf(a[j]); v[4 + j] = (short)f2bf(b[j]); }
            int off = row * 512 + ((seg * 64 + i * 16) ^ ((row & 7) << 4));
            *(short8*)(eb + off) = v;
        }
    }
    __syncthreads();

    for (int t = 0; t < SEQ; ++t) {
        const int cur = t & 1, nxt = cur ^ 1;

        // A: prefetch E_{t+1} into Ebuf[nxt] (independent of the sync)
        {
            int tp = (t + 1 < SEQ) ? (t + 1) : t;
            int row = tid >> 3, seg = tid & 7;
            int tok = X[(b0 + row) * SEQ + tp];
            const float* src = Cemb + (size_t)tok * EMB + seg * 32;
            char* eb = smem + 32768 + nxt * 16384;
#pragma unroll
            for (int i = 0; i < 4; ++i) {
                f32x4 a = *(const f32x4*)(src + i * 8);
                f32x4 b = *(const f32x4*)(src + i * 8 + 4);
                short8 v;
#pragma unroll
                for (int j = 0; j < 4; ++j) { v[j] = (short)f2bf(a[j]); v[4 + j] = (short)f2bf(b[j]); }
                int off = row * 512 + ((seg * 64 + i * 16) ^ ((row & 7) << 4));
                *(short8*)(eb + off) = v;
            }
        }

        // B: x @ W_x{gate} (Ebuf[cur], staged >=2 barriers ago)
        f32x4 acc0 = zero4(), acc1 = zero4();
        {
            const char* eb = smem + 32768 + cur * 16384;
            int r0 = lane & 15, r1 = 16 + r0, sw = (r0 & 7) << 4;
#pragma unroll
            for (int ks = 0; ks < 8; ++ks) {
                int inner = ks * 64 + (lane >> 4) * 16;
                short8 a0 = *(const short8*)(eb + r0 * 512 + (inner ^ sw));
                short8 a1 = *(const short8*)(eb + r1 * 512 + (inner ^ sw));
                acc0 = __builtin_amdgcn_mfma_f32_16x16x32_bf16(a0, bregX[ks], acc0, 0, 0, 0);
                acc1 = __builtin_amdgcn_mfma_f32_16x16x32_bf16(a1, bregX[ks], acc1, 0, 0, 0);
            }
        }

        // C: H @ W_h{gate} (needs all 32 wgs of this bc done with step t-1)
        if (t > 0) {
            if (tid == 0) {
                unsigned target = 32u * (unsigned)t;
                int guard = 0;
                while (__hip_atomic_load(cnt + bc, __ATOMIC_ACQUIRE,
                                         __HIP_MEMORY_SCOPE_AGENT) < target) {
                    __builtin_amdgcn_s_sleep(1);
                    if (++guard > (1 << 18)) break;   // safety: never hang
                }
                __threadfence();                       // acquire
            }
            __syncthreads();
            const u16* Hsrc = Hbuf + cur * (BATCH * HID);
#pragma unroll
            for (int i = 0; i < 8; ++i) {
                int elem = i * 2048 + tid * 8;
                int b = elem >> 9, k = elem & 511;
                short8 v = *(const short8*)(Hsrc + (b0 + b) * HID + k);
                int off = b * 1024 + ((k * 2) ^ ((b & 7) << 4));
                *(short8*)((char*)HA + off) = v;
            }
            __syncthreads();
            int r0 = lane & 15, r1 = 16 + r0, sw = (r0 & 7) << 4;
#pragma unroll
            for (int ks = 0; ks < 16; ++ks) {
                int inner = ks * 64 + (lane >> 4) * 16;
                short8 a0 = *(const short8*)((const char*)HA + r0 * 1024 + (inner ^ sw));
                short8 a1 = *(const short8*)((const char*)HA + r1 * 1024 + (inner ^ sw));
                acc0 = __builtin_amdgcn_mfma_f32_16x16x32_bf16(a0, bregH[ks], acc0, 0, 0, 0);
                acc1 = __builtin_amdgcn_mfma_f32_16x16x32_bf16(a1, bregH[ks], acc1, 0, 0, 0);
            }
        }

        // D: publish pre-activations (D layout: col=lane&15, row=(lane>>4)*4+r)
        {
            int n = wave * 16 + (lane & 15);
#pragma unroll
            for (int r = 0; r < 4; ++r) {
                pre[n * 33 + (lane >> 4) * 4 + r]      = acc0[r];
                pre[n * 33 + 16 + (lane >> 4) * 4 + r] = acc1[r];
            }
        }
        __syncthreads();

        // E: gate math + H publish
        u16* Hdst = Hbuf + nxt * (BATCH * HID);
#pragma unroll
        for (int rep = 0; rep < 2; ++rep) {
            int b = ebl + rep * 16;
            float pi = pre[(0  + ec) * 33 + b] + bias_i;
            float pf = pre[(16 + ec) * 33 + b] + bias_f;
            float po = pre[(32 + ec) * 33 + b] + bias_o;
            float pc = pre[(48 + ec) * 33 + b] + bias_c;
            float I = sigm(pi), F = sigm(pf), O = sigm(po), Ct = tanh_(pc);
            float Cn = F * Cst[b * 16 + ec] + I * Ct;
            Cst[b * 16 + ec] = Cn;
            Hdst[(b0 + b) * HID + cc * 16 + ec] = f2bf(O * tanh_(Cn));
        }
        __syncthreads();                   // drains all waves' H stores (vmcnt 0)
        if (tid == 0) {
            __threadfence();               // release: writeback before signal
            __hip_atomic_fetch_add(cnt + bc, 1u, __ATOMIC_RELEASE,
                                   __HIP_MEMORY_SCOPE_AGENT);
        }
    }
}

// ---------------------------------------------------------------------------
// logits[128][50257] = H_final @ W_hq + b_q. H_final = Hbuf[0] (bf16),
// W_hq/bq f32, out f32.
// ---------------------------------------------------------------------------
__global__ __launch_bounds__(256) void proj_kernel(
    const u16* __restrict__ Hfin, const float* __restrict__ Whq,
    const float* __restrict__ bq, float* __restrict__ out)
{
    __shared__ __align__(16) u16 Alds[128 * 256];   // 64 KB
    const int n0   = blockIdx.x * 128;
    const int tid  = threadIdx.x;
    const int lane = tid & 63;
    const int wave = tid >> 6;

    f32x4 acc[8][2];
#pragma unroll
    for (int m = 0; m < 8; ++m) { acc[m][0] = zero4(); acc[m][1] = zero4(); }

    for (int half = 0; half < 2; ++half) {
        int k0 = half * 256;
        {
            int row = tid >> 1, hh = tid & 1;
            const u16* src = Hfin + row * HID + k0 + hh * 128;
#pragma unroll
            for (int i = 0; i < 16; ++i) {
                short8 v = *(const short8*)(src + i * 8);
                int byte_off = row * 512 + ((hh * 256 + i * 16) ^ ((row & 7) << 4));
                *(short8*)((char*)Alds + byte_off) = v;
            }
        }
        __syncthreads();

        const int col0 = wave * 32;
        for (int ks = 0; ks < 8; ++ks) {
            short8 bfrag[2];
#pragma unroll
            for (int nf = 0; nf < 2; ++nf) {
                int n  = n0 + col0 + nf * 16 + (lane & 15);
                int nc = (n < NCLS) ? n : (NCLS - 1);
                int kb = k0 + ks * 32 + (lane >> 4) * 8;
                short8 v;
#pragma unroll
                for (int j = 0; j < 8; ++j)
                    v[j] = (short)f2bf(Whq[(size_t)(kb + j) * NCLS + nc]);
                bfrag[nf] = v;
            }
#pragma unroll
            for (int mf = 0; mf < 8; ++mf) {
                int row = mf * 16 + (lane & 15);
                int byte_off = row * 512 + ((ks * 64 + (lane >> 4) * 16) ^ ((row & 7) << 4));
                short8 a = *(const short8*)((const char*)Alds + byte_off);
                acc[mf][0] = __builtin_amdgcn_mfma_f32_16x16x32_bf16(a, bfrag[0], acc[mf][0], 0, 0, 0);
                acc[mf][1] = __builtin_amdgcn_mfma_f32_16x16x32_bf16(a, bfrag[1], acc[mf][1], 0, 0, 0);
            }
        }
        __syncthreads();
    }
#pragma unroll
    for (int nf = 0; nf < 2; ++nf) {
        int col = wave * 32 + nf * 16 + (lane & 15);
        int n = n0 + col;
        if (n < NCLS) {
            float bias = bq[n];
#pragma unroll
            for (int mf = 0; mf < 8; ++mf)
#pragma unroll
                for (int r = 0; r < 4; ++r) {
                    int b = mf * 16 + (lane >> 4) * 4 + r;
                    out[(size_t)b * NCLS + n] = acc[mf][nf][r] + bias;
                }
        }
    }
}

// ---------------------------------------------------------------------------
extern "C" void kernel_launch(void* const* d_in, const int* in_sizes, int n_in,
                              void* d_out, int out_size, void* d_ws, size_t ws_size,
                              hipStream_t stream)
{
    (void)in_sizes; (void)n_in; (void)out_size; (void)ws_size;
    const int*   X    = (const int*)d_in[0];
    const float* Cemb = (const float*)d_in[1];
    const float* Wxi  = (const float*)d_in[2];
    const float* Wxf  = (const float*)d_in[3];
    const float* Wxo  = (const float*)d_in[4];
    const float* Wxc  = (const float*)d_in[5];
    const float* Whi  = (const float*)d_in[6];
    const float* Whf  = (const float*)d_in[7];
    const float* Who  = (const float*)d_in[8];
    const float* Whc  = (const float*)d_in[9];
    const float* bi   = (const float*)d_in[10];
    const float* bfv  = (const float*)d_in[11];
    const float* bo   = (const float*)d_in[12];
    const float* bcv  = (const float*)d_in[13];
    const float* Whq  = (const float*)d_in[14];
    const float* bq   = (const float*)d_in[15];
    float* out = (float*)d_out;

    char* ws = (char*)d_ws;
    u16* Hbuf = (u16*)ws;                          // 2*128*512*2 = 262144 B
    unsigned* cnt = (unsigned*)(ws + 262144);      // 256 B

    hipMemsetAsync(cnt, 0, 256, stream);
    void* args[] = {(void*)&X, (void*)&Cemb,
                    (void*)&Wxi, (void*)&Wxf, (void*)&Wxo, (void*)&Wxc,
                    (void*)&Whi, (void*)&Whf, (void*)&Who, (void*)&Whc,
                    (void*)&bi, (void*)&bfv, (void*)&bo, (void*)&bcv,
                    (void*)&Hbuf, (void*)&cnt};
    hipLaunchCooperativeKernel(reinterpret_cast<void*>(rnn_kernel),
                               dim3(128), dim3(256), args, 0, stream);
    proj_kernel<<<(NCLS + 127) / 128, 256, 0, stream>>>(Hbuf, Whq, bq, out);
}

// Round 4
// 1153.371 us; speedup vs baseline: 3.1949x; 3.1949x over previous
//
#include <hip/hip_runtime.h>
#include <hip/hip_bf16.h>

#define BATCH 128
#define SEQ   256
#define EMB   256
#define HID   512
#define NCLS  50257

typedef unsigned short u16;
typedef __attribute__((ext_vector_type(8))) short short8;
typedef __attribute__((ext_vector_type(4))) short s16x4;
typedef __attribute__((ext_vector_type(4))) float f32x4;
typedef __attribute__((ext_vector_type(4))) int   i32x4;

__device__ __forceinline__ u16 f2bf(float f) {
    unsigned x = __builtin_bit_cast(unsigned, f);
    x += 0x7FFFu + ((x >> 16) & 1u);
    return (u16)(x >> 16);
}
__device__ __forceinline__ float sigm(float x) { return 1.f / (1.f + __expf(-x)); }
__device__ __forceinline__ float tanh_(float x) {
    x = fminf(15.f, fmaxf(-15.f, x));
    float e = __expf(2.f * x);
    return (e - 1.f) / (e + 1.f);
}
__device__ __forceinline__ f32x4 zero4() { f32x4 v; v[0]=0.f; v[1]=0.f; v[2]=0.f; v[3]=0.f; return v; }

// ---------------------------------------------------------------------------
// Fused LSTM recurrence. Cooperative, 128 wgs: wg=(bc 0..3)x(cc 0..31) owns
// batch rows [32*bc,+32) and H-cols [16*cc,+16). One gate per wave; W_x and
// W_h slices in VGPRs. Cross-wg H exchange goes through L3 ONLY (sc0 sc1
// write-through stores + cache-bypass loads) -> no buffer_wbl2/buffer_inv
// per step, L2 keeps Cemb/weights hot. Sync: per-wg flag words (no RMW),
// wave-0 collective poll.
// LDS map (bytes): [0,32768) HA = H tile [32][1024B] swz (also 1-time weight
// staging); [32768,65536) E0/E1 [32][512B] swz; [65536,73984) pre[64][33]f32;
// [73984,76032) Cst[32][16]f32.
// ---------------------------------------------------------------------------
__global__ __launch_bounds__(256, 1) void rnn_kernel(
    const int* __restrict__ X, const float* __restrict__ Cemb,
    const float* __restrict__ Wxi, const float* __restrict__ Wxf,
    const float* __restrict__ Wxo, const float* __restrict__ Wxc,
    const float* __restrict__ Whi, const float* __restrict__ Whf,
    const float* __restrict__ Who, const float* __restrict__ Whc,
    const float* __restrict__ bi, const float* __restrict__ bfv,
    const float* __restrict__ bo, const float* __restrict__ bcv,
    unsigned* __restrict__ Hbuf, unsigned* __restrict__ flags)
{
    __shared__ __align__(16) char smem[76032];
    u16*   HA  = (u16*)smem;
    float* pre = (float*)(smem + 65536);
    float* Cst = (float*)(smem + 73984);

    const int wg = blockIdx.x;
    const int bc = wg >> 5, cc = wg & 31, b0 = bc * 32;
    const int tid = threadIdx.x, lane = tid & 63, wave = tid >> 6;

    // phase-E decomposition: thread <-> (row pb 0..31, col-pair pp 0..7)
    const int pb = tid >> 3, pp = tid & 7;
    const int c0 = pp << 1, c1 = c0 + 1;

    const float* WxA[4] = {Wxi, Wxf, Wxo, Wxc};
    const float* WhA[4] = {Whi, Whf, Who, Whc};

    const float bi0 = bi [cc * 16 + c0], bi1 = bi [cc * 16 + c1];
    const float bf0 = bfv[cc * 16 + c0], bf1 = bfv[cc * 16 + c1];
    const float bo0 = bo [cc * 16 + c0], bo1 = bo [cc * 16 + c1];
    const float bc0 = bcv[cc * 16 + c0], bc1 = bcv[cc * 16 + c1];

    // ---- one-time: W_x slice [256 k][16 n] (f32 -> bf16) -> bregX ----
    short8 bregX[8];
    {
        const float* Wx = WxA[wave];
        u16* dst = HA + wave * 4096;
#pragma unroll
        for (int it = 0; it < 16; ++it) {
            int e = it * 256 + lane * 4;
            int k = e >> 4, cq = (e & 15) >> 2;
            f32x4 v = *(const f32x4*)(Wx + (size_t)k * HID + cc * 16 + cq * 4);
            s16x4 s;
#pragma unroll
            for (int j = 0; j < 4; ++j) s[j] = (short)f2bf(v[j]);
            *(s16x4*)(dst + k * 16 + cq * 4) = s;
        }
    }
    __syncthreads();
    {
        const u16* tile = HA + wave * 4096;
#pragma unroll
        for (int ks = 0; ks < 8; ++ks) {
            short8 v;
#pragma unroll
            for (int i = 0; i < 8; ++i)
                v[i] = (short)tile[(ks * 32 + (lane >> 4) * 8 + i) * 16 + (lane & 15)];
            bregX[ks] = v;
        }
    }
    __syncthreads();

    // ---- one-time: W_h slice [512 k][16 n] per gate -> bregH (2 passes) ----
    short8 bregH[16];
    for (int pass = 0; pass < 2; ++pass) {
        for (int gi = 0; gi < 2; ++gi) {
            const float* W = WhA[2 * pass + gi];
#pragma unroll
            for (int it = 0; it < 8; ++it) {
                int e = it * 1024 + tid * 4;
                int k = e >> 4, cq = (e & 15) >> 2;
                f32x4 v = *(const f32x4*)(W + (size_t)k * HID + cc * 16 + cq * 4);
                s16x4 s;
#pragma unroll
                for (int j = 0; j < 4; ++j) s[j] = (short)f2bf(v[j]);
                *(s16x4*)(HA + gi * 8192 + k * 16 + cq * 4) = s;
            }
        }
        __syncthreads();
        if ((wave >> 1) == pass) {
            const u16* tile = HA + (wave & 1) * 8192;
#pragma unroll
            for (int ks = 0; ks < 16; ++ks) {
                short8 v;
#pragma unroll
                for (int i = 0; i < 8; ++i)
                    v[i] = (short)tile[(ks * 32 + (lane >> 4) * 8 + i) * 16 + (lane & 15)];
                bregH[ks] = v;
            }
        }
        __syncthreads();
    }

    // ---- Cst = 0, stage E_0 into buf 0 ----
    for (int i = tid; i < 512; i += 256) Cst[i] = 0.f;
    {
        int row = tid >> 3, seg = tid & 7;
        int tok = X[(b0 + row) * SEQ + 0];
        const float* src = Cemb + (size_t)tok * EMB + seg * 32;
        char* eb = smem + 32768;
#pragma unroll
        for (int i = 0; i < 4; ++i) {
            f32x4 a = *(const f32x4*)(src + i * 8);
            f32x4 b = *(const f32x4*)(src + i * 8 + 4);
            short8 v;
#pragma unroll
            for (int j = 0; j < 4; ++j) { v[j] = (short)f2bf(a[j]); v[4 + j] = (short)f2bf(b[j]); }
            int off = row * 512 + ((seg * 64 + i * 16) ^ ((row & 7) << 4));
            *(short8*)(eb + off) = v;
        }
    }
    __syncthreads();

    for (int t = 0; t < SEQ; ++t) {
        const int cur = t & 1, nxt = cur ^ 1;

        // A: prefetch E_{t+1} into Ebuf[nxt] (plain loads; L2-resident now)
        {
            int tp = (t + 1 < SEQ) ? (t + 1) : t;
            int row = tid >> 3, seg = tid & 7;
            int tok = X[(b0 + row) * SEQ + tp];
            const float* src = Cemb + (size_t)tok * EMB + seg * 32;
            char* eb = smem + 32768 + nxt * 16384;
#pragma unroll
            for (int i = 0; i < 4; ++i) {
                f32x4 a = *(const f32x4*)(src + i * 8);
                f32x4 b = *(const f32x4*)(src + i * 8 + 4);
                short8 v;
#pragma unroll
                for (int j = 0; j < 4; ++j) { v[j] = (short)f2bf(a[j]); v[4 + j] = (short)f2bf(b[j]); }
                int off = row * 512 + ((seg * 64 + i * 16) ^ ((row & 7) << 4));
                *(short8*)(eb + off) = v;
            }
        }

        // B: x @ W_x{gate} (Ebuf[cur])
        f32x4 acc0 = zero4(), acc1 = zero4();
        {
            const char* eb = smem + 32768 + cur * 16384;
            int r0 = lane & 15, r1 = 16 + r0, sw = (r0 & 7) << 4;
#pragma unroll
            for (int ks = 0; ks < 8; ++ks) {
                int inner = ks * 64 + (lane >> 4) * 16;
                short8 a0 = *(const short8*)(eb + r0 * 512 + (inner ^ sw));
                short8 a1 = *(const short8*)(eb + r1 * 512 + (inner ^ sw));
                acc0 = __builtin_amdgcn_mfma_f32_16x16x32_bf16(a0, bregX[ks], acc0, 0, 0, 0);
                acc1 = __builtin_amdgcn_mfma_f32_16x16x32_bf16(a1, bregX[ks], acc1, 0, 0, 0);
            }
        }

        // C: H @ W_h{gate} — wait for step t-1 of this bc, then stage H
        if (t > 0) {
            if (wave == 0) {
                const unsigned* fp = flags + bc * 32 + (lane & 31);
                unsigned target = (unsigned)t;
                int guard = 0;
                unsigned v = 0;
                do {
                    asm volatile("global_load_dword %0, %1, off sc0 sc1\n\t"
                                 "s_waitcnt vmcnt(0)"
                                 : "=v"(v) : "v"(fp) : "memory");
                } while (!__all(v >= target) && ++guard < (1 << 17));
            }
            __syncthreads();

            const unsigned* Hsrc = Hbuf + cur * 32768;
            i32x4 h[8];
#pragma unroll
            for (int i = 0; i < 8; ++i) {
                int elem = i * 2048 + tid * 8;
                int b = elem >> 9, k = elem & 511;
                const unsigned* p = Hsrc + (b0 + b) * 256 + (k >> 1);
                asm volatile("global_load_dwordx4 %0, %1, off sc0 sc1"
                             : "=v"(h[i]) : "v"(p));
            }
            asm volatile("s_waitcnt vmcnt(0)" ::: "memory");
            __builtin_amdgcn_sched_barrier(0);
#pragma unroll
            for (int i = 0; i < 8; ++i) {
                int elem = i * 2048 + tid * 8;
                int b = elem >> 9, k = elem & 511;
                int off = b * 1024 + ((k * 2) ^ ((b & 7) << 4));
                *(short8*)((char*)HA + off) = __builtin_bit_cast(short8, h[i]);
            }
            __syncthreads();

            int r0 = lane & 15, r1 = 16 + r0, sw = (r0 & 7) << 4;
#pragma unroll
            for (int ks = 0; ks < 16; ++ks) {
                int inner = ks * 64 + (lane >> 4) * 16;
                short8 a0 = *(const short8*)((const char*)HA + r0 * 1024 + (inner ^ sw));
                short8 a1 = *(const short8*)((const char*)HA + r1 * 1024 + (inner ^ sw));
                acc0 = __builtin_amdgcn_mfma_f32_16x16x32_bf16(a0, bregH[ks], acc0, 0, 0, 0);
                acc1 = __builtin_amdgcn_mfma_f32_16x16x32_bf16(a1, bregH[ks], acc1, 0, 0, 0);
            }
        }

        // D: publish pre-activations (D layout: col=lane&15, row=(lane>>4)*4+r)
        {
            int n = wave * 16 + (lane & 15);
#pragma unroll
            for (int r = 0; r < 4; ++r) {
                pre[n * 33 + (lane >> 4) * 4 + r]      = acc0[r];
                pre[n * 33 + 16 + (lane >> 4) * 4 + r] = acc1[r];
            }
        }
        __syncthreads();

        // E: gate math + H publish (write-through to L3), flag release
        {
            float pi0 = pre[(0  + c0) * 33 + pb] + bi0;
            float pi1 = pre[(0  + c1) * 33 + pb] + bi1;
            float pf0 = pre[(16 + c0) * 33 + pb] + bf0;
            float pf1 = pre[(16 + c1) * 33 + pb] + bf1;
            float po0 = pre[(32 + c0) * 33 + pb] + bo0;
            float po1 = pre[(32 + c1) * 33 + pb] + bo1;
            float pc0 = pre[(48 + c0) * 33 + pb] + bc0;
            float pc1 = pre[(48 + c1) * 33 + pb] + bc1;
            float I0 = sigm(pi0), F0 = sigm(pf0), O0 = sigm(po0), T0 = tanh_(pc0);
            float I1 = sigm(pi1), F1 = sigm(pf1), O1 = sigm(po1), T1 = tanh_(pc1);
            float Cn0 = F0 * Cst[pb * 16 + c0] + I0 * T0;  Cst[pb * 16 + c0] = Cn0;
            float Cn1 = F1 * Cst[pb * 16 + c1] + I1 * T1;  Cst[pb * 16 + c1] = Cn1;
            float H0 = O0 * tanh_(Cn0), H1 = O1 * tanh_(Cn1);
            unsigned pack = (unsigned)f2bf(H0) | ((unsigned)f2bf(H1) << 16);
            unsigned* dst = Hbuf + nxt * 32768 + (b0 + pb) * 256 + cc * 8 + pp;
            asm volatile("global_store_dword %0, %1, off sc0 sc1\n\t"
                         "s_waitcnt vmcnt(0)"
                         :: "v"(dst), "v"(pack) : "memory");
        }
        __syncthreads();                   // all waves' stores at L3
        if (tid == 0) {
            unsigned* fp = flags + bc * 32 + cc;
            unsigned val = (unsigned)(t + 1);
            asm volatile("global_store_dword %0, %1, off sc0 sc1"
                         :: "v"(fp), "v"(val) : "memory");
        }
    }
}

// ---------------------------------------------------------------------------
// logits[128][50257] = H_final @ W_hq + b_q. H_final = Hbuf[0] (bf16 view),
// W_hq/bq f32, out f32.
// ---------------------------------------------------------------------------
__global__ __launch_bounds__(256) void proj_kernel(
    const u16* __restrict__ Hfin, const float* __restrict__ Whq,
    const float* __restrict__ bq, float* __restrict__ out)
{
    __shared__ __align__(16) u16 Alds[128 * 256];   // 64 KB
    const int n0   = blockIdx.x * 128;
    const int tid  = threadIdx.x;
    const int lane = tid & 63;
    const int wave = tid >> 6;

    f32x4 acc[8][2];
#pragma unroll
    for (int m = 0; m < 8; ++m) { acc[m][0] = zero4(); acc[m][1] = zero4(); }

    for (int half = 0; half < 2; ++half) {
        int k0 = half * 256;
        {
            int row = tid >> 1, hh = tid & 1;
            const u16* src = Hfin + row * HID + k0 + hh * 128;
#pragma unroll
            for (int i = 0; i < 16; ++i) {
                short8 v = *(const short8*)(src + i * 8);
                int byte_off = row * 512 + ((hh * 256 + i * 16) ^ ((row & 7) << 4));
                *(short8*)((char*)Alds + byte_off) = v;
            }
        }
        __syncthreads();

        const int col0 = wave * 32;
        for (int ks = 0; ks < 8; ++ks) {
            short8 bfrag[2];
#pragma unroll
            for (int nf = 0; nf < 2; ++nf) {
                int n  = n0 + col0 + nf * 16 + (lane & 15);
                int nc = (n < NCLS) ? n : (NCLS - 1);
                int kb = k0 + ks * 32 + (lane >> 4) * 8;
                short8 v;
#pragma unroll
                for (int j = 0; j < 8; ++j)
                    v[j] = (short)f2bf(Whq[(size_t)(kb + j) * NCLS + nc]);
                bfrag[nf] = v;
            }
#pragma unroll
            for (int mf = 0; mf < 8; ++mf) {
                int row = mf * 16 + (lane & 15);
                int byte_off = row * 512 + ((ks * 64 + (lane >> 4) * 16) ^ ((row & 7) << 4));
                short8 a = *(const short8*)((const char*)Alds + byte_off);
                acc[mf][0] = __builtin_amdgcn_mfma_f32_16x16x32_bf16(a, bfrag[0], acc[mf][0], 0, 0, 0);
                acc[mf][1] = __builtin_amdgcn_mfma_f32_16x16x32_bf16(a, bfrag[1], acc[mf][1], 0, 0, 0);
            }
        }
        __syncthreads();
    }
#pragma unroll
    for (int nf = 0; nf < 2; ++nf) {
        int col = wave * 32 + nf * 16 + (lane & 15);
        int n = n0 + col;
        if (n < NCLS) {
            float bias = bq[n];
#pragma unroll
            for (int mf = 0; mf < 8; ++mf)
#pragma unroll
                for (int r = 0; r < 4; ++r) {
                    int b = mf * 16 + (lane >> 4) * 4 + r;
                    out[(size_t)b * NCLS + n] = acc[mf][nf][r] + bias;
                }
        }
    }
}

// ---------------------------------------------------------------------------
extern "C" void kernel_launch(void* const* d_in, const int* in_sizes, int n_in,
                              void* d_out, int out_size, void* d_ws, size_t ws_size,
                              hipStream_t stream)
{
    (void)in_sizes; (void)n_in; (void)out_size; (void)ws_size;
    const int*   X    = (const int*)d_in[0];
    const float* Cemb = (const float*)d_in[1];
    const float* Wxi  = (const float*)d_in[2];
    const float* Wxf  = (const float*)d_in[3];
    const float* Wxo  = (const float*)d_in[4];
    const float* Wxc  = (const float*)d_in[5];
    const float* Whi  = (const float*)d_in[6];
    const float* Whf  = (const float*)d_in[7];
    const float* Who  = (const float*)d_in[8];
    const float* Whc  = (const float*)d_in[9];
    const float* bi   = (const float*)d_in[10];
    const float* bfv  = (const float*)d_in[11];
    const float* bo   = (const float*)d_in[12];
    const float* bcv  = (const float*)d_in[13];
    const float* Whq  = (const float*)d_in[14];
    const float* bq   = (const float*)d_in[15];
    float* out = (float*)d_out;

    char* ws = (char*)d_ws;
    unsigned* Hbuf  = (unsigned*)ws;               // 2*128*256*4 = 262144 B
    unsigned* flags = (unsigned*)(ws + 262144);    // 128*4 = 512 B

    hipMemsetAsync(flags, 0, 512, stream);
    void* args[] = {(void*)&X, (void*)&Cemb,
                    (void*)&Wxi, (void*)&Wxf, (void*)&Wxo, (void*)&Wxc,
                    (void*)&Whi, (void*)&Whf, (void*)&Who, (void*)&Whc,
                    (void*)&bi, (void*)&bfv, (void*)&bo, (void*)&bcv,
                    (void*)&Hbuf, (void*)&flags};
    hipLaunchCooperativeKernel(reinterpret_cast<void*>(rnn_kernel),
                               dim3(128), dim3(256), args, 0, stream);
    proj_kernel<<<(NCLS + 127) / 128, 256, 0, stream>>>((const u16*)ws, Whq, bq, out);
}